// Round 1
// 1079.428 us; speedup vs baseline: 1.0052x; 1.0052x over previous
//
#include <hip/hip_runtime.h>
#include <hip/hip_bf16.h>
#include <math.h>

// ---------------- problem constants ----------------
#define BN 4096
#define DN 256
#define SN 32
#define KN 8192
#define AN 256
#define TWO_D 512

typedef unsigned short ushort;
using bf16x8 = __attribute__((ext_vector_type(8))) short;
using f32x4  = __attribute__((ext_vector_type(4))) float;

// ---------------- output layout (f32 elements, concatenated flat) ------------
#define OUT_MAIN 0ull                       // [B,5,512] = 10485760
#define OUT_NMR  10485760ull                // [B,32,256] = 33554432
#define OUT_NMI  44040192ull
#define OUT_IDX  77594624ull                // [B]
#define OUT_VQL  77598720ull                // [B]
#define OUT_BENT 77602816ull
#define OUT_SENT 77602817ull

// ---------------- ws layout (bytes), total 93MB ----------------
#define MBYTE (1024ull*1024ull)
#define WS_GR    (0ull)            // f32 [B*256]   4MB
#define WS_GI    (4ull*MBYTE)      // f32           4MB
#define WS_Z2H   (8ull*MBYTE)      // u16 [B*512]   4MB
#define WS_Z2L   (12ull*MBYTE)     // u16           4MB
#define WS_EH    (16ull*MBYTE)     // u16 [K*512]   8MB
#define WS_EL    (24ull*MBYTE)     // u16           8MB
#define WS_E2    (32ull*MBYTE)     // f32 [K]
#define WS_WBIG  (33ull*MBYTE)     // u16 [2560*512] 2.5MB
#define WS_BIAS  (36ull*MBYTE)     // f32 [2560]
#define WS_PALC  (37ull*MBYTE)     // u16 [512*512] 0.5MB
#define WS_VIST  (38ull*MBYTE)     // u16 [512*256]
#define WS_AUDT  (39ull*MBYTE)     // u16 [512*256]
#define WS_PVAL  (40ull*MBYTE)     // f32 [4096*128] 2MB
#define WS_PIDX  (42ull*MBYTE)     // i32 [4096*128] 2MB
#define WS_HIST  (44ull*MBYTE)     // i32 [8192]
#define WS_SENT  (44ull*MBYTE + 64ull*1024ull) // f32 [1]
#define WS_CL    (45ull*MBYTE)     // u16 [4096*2560] 20MB
#define WS_LOGIT (65ull*MBYTE)     // f32 [4096*512] 8MB
#define WS_ATTN  (73ull*MBYTE)     // u16 [4096*512] 4MB
#define WS_VIS   (77ull*MBYTE)     // f32 [4096*512] 8MB
#define WS_AUD   (85ull*MBYTE)     // f32 [4096*512] 8MB -> 93MB total

#define DEVINL __device__ __forceinline__

DEVINL ushort f2bf(float f) {
    union { float f; unsigned u; } v; v.f = f;
    unsigned r = v.u + 0x7fffu + ((v.u >> 16) & 1u);
    return (ushort)(r >> 16);
}
DEVINL float bf2f(ushort h) {
    union { unsigned u; float f; } v; v.u = ((unsigned)h) << 16;
    return v.f;
}
DEVINL float sigmoidf_(float x) { return 1.f / (1.f + __expf(-x)); }

// =====================================================================
// prep: split vq_emb into bf16 hi/lo + row norms  (1 wave per code row)
// =====================================================================
__global__ __launch_bounds__(256) void k_prep_vq(const float* __restrict__ emb,
                                                 ushort* __restrict__ eh,
                                                 ushort* __restrict__ el,
                                                 float* __restrict__ e2) {
    int t = threadIdx.x, w = t >> 6, lane = t & 63;
    int row = blockIdx.x * 4 + w;
    const float* er = emb + (size_t)row * 512;
    float acc = 0.f;
    #pragma unroll
    for (int j = 0; j < 8; j++) {
        int k = lane + 64 * j;
        float e = er[k];
        ushort h = f2bf(e);
        eh[(size_t)row * 512 + k] = h;
        el[(size_t)row * 512 + k] = f2bf(e - bf2f(h));
        acc += e * e;
    }
    for (int m = 1; m < 64; m <<= 1) acc += __shfl_xor(acc, m, 64);
    if (lane == 0) e2[row] = acc;
}

// =====================================================================
// prep: one complex-linear block of Wbig (512 rows x 512 cols) + bias
// =====================================================================
__global__ void k_prep_wbig(const float* __restrict__ Wr, const float* __restrict__ Wi,
                            const float* __restrict__ br, const float* __restrict__ bi,
                            ushort* __restrict__ Wb, float* __restrict__ bias) {
    int idx = blockIdx.x * 256 + threadIdx.x;   // < 512*512
    int j = idx >> 9, k = idx & 511;
    int part = j >> 8, jj = j & 255;
    float v;
    if (part == 0) v = (k < 256) ? Wr[jj * 256 + k] : -Wi[jj * 256 + (k - 256)];
    else           v = (k < 256) ? Wi[jj * 256 + k] :  Wr[jj * 256 + (k - 256)];
    Wb[idx] = f2bf(v);
    if (k == 0) bias[j] = part ? (br[jj] + bi[jj]) : (br[jj] - bi[jj]);
}

__global__ void k_prep_palcat(const float* __restrict__ vis, const float* __restrict__ aud,
                              ushort* __restrict__ palc) {
    int idx = blockIdx.x * 256 + threadIdx.x;   // < 512*512
    int a = idx >> 9, k = idx & 511;
    float v = (a < 256) ? vis[a * 512 + k] : aud[(a - 256) * 512 + k];
    palc[idx] = f2bf(v);
}
__global__ void k_prep_palT(const float* __restrict__ vis, const float* __restrict__ aud,
                            ushort* __restrict__ visT, ushort* __restrict__ audT) {
    int idx = blockIdx.x * 256 + threadIdx.x;   // < 512*256
    int j = idx >> 8, a = idx & 255;
    visT[j * 256 + a] = f2bf(vis[a * 512 + j]);
    audT[j * 256 + a] = f2bf(aud[a * 512 + j]);
}

// =====================================================================
// input gate blend
// =====================================================================
__global__ void k_gate(const float* __restrict__ xr, const float* __restrict__ xi,
                       const float* __restrict__ gwr, const float* __restrict__ gwi,
                       const float* __restrict__ ig,
                       float* __restrict__ gr, float* __restrict__ gi,
                       ushort* __restrict__ z2h, ushort* __restrict__ z2l) {
    int i = blockIdx.x * 256 + threadIdx.x;     // < B*256
    float a = sigmoidf_(ig[0]);
    float r  = a * gwr[i] + (1.f - a) * xr[i];
    float im = a * gwi[i] + (1.f - a) * xi[i];
    gr[i] = r; gi[i] = im;
    int b = i >> 8, d = i & 255;
    size_t z = (size_t)b * 512;
    ushort rh = f2bf(r);  z2h[z + d] = rh;       z2l[z + d] = f2bf(r - bf2f(rh));
    ushort ih = f2bf(im); z2h[z + 256 + d] = ih; z2l[z + 256 + d] = f2bf(im - bf2f(ih));
}

// =====================================================================
// VQ GEMM (bf16x3) + per-row per-64col-slot argmin of (|e|^2 - 2 z.e)
// =====================================================================
__global__ __launch_bounds__(256) void k_vq_gemm(
    const ushort* __restrict__ Zh, const ushort* __restrict__ Zl,
    const ushort* __restrict__ Eh, const ushort* __restrict__ El,
    const float* __restrict__ e2, float* __restrict__ pval, int* __restrict__ pidx) {
    __shared__ ushort Ah[128 * 40], Al[128 * 40], Bh[128 * 40], Bl[128 * 40];
    const int m0 = blockIdx.y * 128, n0 = blockIdx.x * 128;
    const int t = threadIdx.x;
    const int w = t >> 6, lane = t & 63, q = lane >> 4, ln = lane & 15;
    const int wm = w >> 1, wn = w & 1;
    f32x4 acc[4][4] = {};
    const int lrow = t >> 2, lcol = (t & 3) * 8;
    for (int k0 = 0; k0 < 512; k0 += 32) {
        __syncthreads();
        #pragma unroll
        for (int rep = 0; rep < 2; rep++) {
            int r = lrow + rep * 64;
            *(uint4*)(&Ah[r * 40 + lcol]) = *(const uint4*)(Zh + (size_t)(m0 + r) * 512 + k0 + lcol);
            *(uint4*)(&Al[r * 40 + lcol]) = *(const uint4*)(Zl + (size_t)(m0 + r) * 512 + k0 + lcol);
            *(uint4*)(&Bh[r * 40 + lcol]) = *(const uint4*)(Eh + (size_t)(n0 + r) * 512 + k0 + lcol);
            *(uint4*)(&Bl[r * 40 + lcol]) = *(const uint4*)(El + (size_t)(n0 + r) * 512 + k0 + lcol);
        }
        __syncthreads();
        bf16x8 ah[4], al[4], bh[4], bl[4];
        #pragma unroll
        for (int i = 0; i < 4; i++) {
            int ar = wm * 64 + i * 16 + ln;
            ah[i] = *(const bf16x8*)(&Ah[ar * 40 + q * 8]);
            al[i] = *(const bf16x8*)(&Al[ar * 40 + q * 8]);
            int br = wn * 64 + i * 16 + ln;
            bh[i] = *(const bf16x8*)(&Bh[br * 40 + q * 8]);
            bl[i] = *(const bf16x8*)(&Bl[br * 40 + q * 8]);
        }
        #pragma unroll
        for (int i = 0; i < 4; i++)
            #pragma unroll
            for (int j = 0; j < 4; j++) {
                acc[i][j] = __builtin_amdgcn_mfma_f32_16x16x32_bf16(ah[i], bh[j], acc[i][j], 0, 0, 0);
                acc[i][j] = __builtin_amdgcn_mfma_f32_16x16x32_bf16(ah[i], bl[j], acc[i][j], 0, 0, 0);
                acc[i][j] = __builtin_amdgcn_mfma_f32_16x16x32_bf16(al[i], bh[j], acc[i][j], 0, 0, 0);
            }
    }
    float e2v[4]; int cidx[4];
    #pragma unroll
    for (int j = 0; j < 4; j++) { cidx[j] = n0 + wn * 64 + j * 16 + ln; e2v[j] = e2[cidx[j]]; }
    #pragma unroll
    for (int i = 0; i < 4; i++) {
        #pragma unroll
        for (int reg = 0; reg < 4; reg++) {
            float bv = 3.4e38f; int bc = 0x7fffffff;
            #pragma unroll
            for (int j = 0; j < 4; j++) {
                float s = e2v[j] - 2.f * acc[i][j][reg];
                if (s < bv || (s == bv && cidx[j] < bc)) { bv = s; bc = cidx[j]; }
            }
            for (int m = 1; m < 16; m <<= 1) {
                float ov = __shfl_xor(bv, m, 64);
                int   oc = __shfl_xor(bc, m, 64);
                if (ov < bv || (ov == bv && oc < bc)) { bv = ov; bc = oc; }
            }
            if (ln == 0) {
                int r = m0 + wm * 64 + i * 16 + q * 4 + reg;
                int slot = blockIdx.x * 2 + wn;
                pval[(size_t)r * 128 + slot] = bv;
                pidx[(size_t)r * 128 + slot] = bc;
            }
        }
    }
}

// =====================================================================
// finalize: top-8 by MFMA score, exact f64 rescore, write idx/v_out/vq_loss
// 1 block = 1 row. ALL d_out writes are f32.
// =====================================================================
__global__ __launch_bounds__(256) void k_vqfin(
    const float* __restrict__ pval, const int* __restrict__ pidx,
    const float* __restrict__ emb, const float* __restrict__ gr,
    const float* __restrict__ gi, float* __restrict__ out, int* __restrict__ hist) {
    __shared__ float sz[512];
    __shared__ float sv[128];
    __shared__ int   scd[128];
    __shared__ int   topc[8];
    __shared__ double tsc[8];
    __shared__ int   sbc;
    int b = blockIdx.x, t = threadIdx.x;
    sz[t]       = gr[(size_t)b * 256 + t];
    sz[256 + t] = gi[(size_t)b * 256 + t];
    if (t < 128) { sv[t] = pval[(size_t)b * 128 + t]; scd[t] = pidx[(size_t)b * 128 + t]; }
    __syncthreads();
    if (t == 0) {   // serial top-8 selection among 128 candidates
        for (int j = 0; j < 8; j++) {
            float bv = 3.4e38f; int bi = 0;
            for (int m = 0; m < 128; m++) {
                float v = sv[m];
                if (v < bv || (v == bv && scd[m] < scd[bi])) { bv = v; bi = m; }
            }
            topc[j] = scd[bi];
            sv[bi] = 3.4e38f;
        }
    }
    __syncthreads();
    int w = t >> 6, lane = t & 63;
    for (int rep = 0; rep < 2; rep++) {
        int j = w + rep * 4;
        int c = topc[j];
        const float* e = emb + (size_t)c * 512;
        double acc = 0.0;
        #pragma unroll
        for (int u = 0; u < 8; u++) {
            int k2 = lane + u * 64;
            double d = (double)sz[k2] - (double)e[k2];
            acc += d * d;
        }
        for (int m = 1; m < 64; m <<= 1) acc += __shfl_xor(acc, m, 64);
        if (lane == 0) tsc[j] = acc;
    }
    __syncthreads();
    if (t == 0) {
        double bv = tsc[0]; int bc = topc[0];
        for (int j = 1; j < 8; j++)
            if (tsc[j] < bv || (tsc[j] == bv && topc[j] < bc)) { bv = tsc[j]; bc = topc[j]; }
        sbc = bc;
        out[OUT_IDX + b] = (float)bc;
        out[OUT_VQL + b] = (float)(0.25 * bv / 512.0);
        atomicAdd(&hist[bc], 1);
    }
    __syncthreads();
    const float* e = emb + (size_t)sbc * 512;
    float* om = out + (size_t)b * 2560;
    om[t]       = e[t];
    om[256 + t] = e[256 + t];
}

// =====================================================================
// generic bf16 GEMM: C[MxN] = A[MxKd]*B[NxKd]^T (+bias); f32 or bf16 out
// =====================================================================
__global__ __launch_bounds__(256) void k_gemm(
    const ushort* __restrict__ A, int lda,
    const ushort* __restrict__ Bm, int ldb,
    void* __restrict__ C, int ldc,
    int Kd, const float* __restrict__ bias, int obf) {
    __shared__ ushort As[128 * 40], Bs[128 * 40];
    const int m0 = blockIdx.y * 128, n0 = blockIdx.x * 128;
    const int t = threadIdx.x;
    const int w = t >> 6, lane = t & 63, q = lane >> 4, ln = lane & 15;
    const int wm = w >> 1, wn = w & 1;
    f32x4 acc[4][4] = {};
    const int lrow = t >> 2, lcol = (t & 3) * 8;
    for (int k0 = 0; k0 < Kd; k0 += 32) {
        __syncthreads();
        #pragma unroll
        for (int rep = 0; rep < 2; rep++) {
            int r = lrow + rep * 64;
            *(uint4*)(&As[r * 40 + lcol]) = *(const uint4*)(A + (size_t)(m0 + r) * lda + k0 + lcol);
            *(uint4*)(&Bs[r * 40 + lcol]) = *(const uint4*)(Bm + (size_t)(n0 + r) * ldb + k0 + lcol);
        }
        __syncthreads();
        bf16x8 af[4], bfr[4];
        #pragma unroll
        for (int i = 0; i < 4; i++) {
            af[i]  = *(const bf16x8*)(&As[(wm * 64 + i * 16 + ln) * 40 + q * 8]);
            bfr[i] = *(const bf16x8*)(&Bs[(wn * 64 + i * 16 + ln) * 40 + q * 8]);
        }
        #pragma unroll
        for (int i = 0; i < 4; i++)
            #pragma unroll
            for (int j = 0; j < 4; j++)
                acc[i][j] = __builtin_amdgcn_mfma_f32_16x16x32_bf16(af[i], bfr[j], acc[i][j], 0, 0, 0);
    }
    #pragma unroll
    for (int i = 0; i < 4; i++) {
        int r = m0 + wm * 64 + i * 16 + q * 4;
        #pragma unroll
        for (int j = 0; j < 4; j++) {
            int c = n0 + wn * 64 + j * 16 + ln;
            float bb = bias ? bias[c] : 0.f;
            #pragma unroll
            for (int reg = 0; reg < 4; reg++) {
                float v = acc[i][j][reg] + bb;
                if (obf) ((ushort*)C)[(size_t)(r + reg) * ldc + c] = f2bf(v);
                else     ((float*)C)[(size_t)(r + reg) * ldc + c] = v;
            }
        }
    }
}

// =====================================================================
// hermitian gate epilogue + critic (CL is bf16) ; 1 block = 1 row
// =====================================================================
__global__ __launch_bounds__(256) void k_hermit(const ushort* __restrict__ CL,
                                                float* __restrict__ out) {
    int b = blockIdx.x, t = threadIdx.x;
    const ushort* row = CL + (size_t)b * 2560;
    float qr = bf2f(row[t]), qi = bf2f(row[256 + t]);
    float kr = bf2f(row[512 + t]), ki = bf2f(row[768 + t]);
    float part = qr * kr + qi * ki;
    __shared__ float red[4];
    for (int m = 1; m < 64; m <<= 1) part += __shfl_xor(part, m, 64);
    if ((t & 63) == 0) red[t >> 6] = part;
    __syncthreads();
    float gate = sigmoidf_(red[0] + red[1] + red[2] + red[3]);
    float vr = bf2f(row[1024 + t]), vi = bf2f(row[1280 + t]);
    float* om = out + (size_t)b * 2560;
    om[512 + t] = vr * gate; om[512 + 256 + t] = vi * gate;
    float crr = bf2f(row[2048 + t]), cii = bf2f(row[2304 + t]);
    om[4 * 512 + t] = -cii; om[4 * 512 + 256 + t] = crr;
}

// =====================================================================
// palette softmax over each 256-half (1 block = 1 row)
// =====================================================================
__global__ __launch_bounds__(256) void k_smax(const float* __restrict__ L,
                                              ushort* __restrict__ attn) {
    int b = blockIdx.x, t = threadIdx.x;
    __shared__ float sred[8];
    for (int h = 0; h < 2; h++) {
        float x = L[(size_t)b * 512 + h * 256 + t];
        float mx = x;
        for (int m = 1; m < 64; m <<= 1) mx = fmaxf(mx, __shfl_xor(mx, m, 64));
        if ((t & 63) == 0) sred[t >> 6] = mx;
        __syncthreads();
        mx = fmaxf(fmaxf(sred[0], sred[1]), fmaxf(sred[2], sred[3]));
        float e = __expf(x - mx);
        float su = e;
        for (int m = 1; m < 64; m <<= 1) su += __shfl_xor(su, m, 64);
        if ((t & 63) == 0) sred[4 + (t >> 6)] = su;
        __syncthreads();
        su = sred[4] + sred[5] + sred[6] + sred[7];
        attn[(size_t)b * 512 + h * 256 + t] = f2bf(e / su);
        __syncthreads();
    }
}

__global__ void k_sout(const float* __restrict__ vis, const float* __restrict__ aud,
                       float* __restrict__ out) {
    int i = blockIdx.x * 256 + threadIdx.x;  // < B*256
    int b = i >> 8, d = i & 255;
    const float* v = vis + (size_t)b * 512;
    const float* a = aud + (size_t)b * 512;
    float* om = out + (size_t)b * 2560 + 3 * 512;
    om[d]       = v[d] - a[256 + d];
    om[256 + d] = v[256 + d] + a[d];
}

// =====================================================================
// fused associative memory — REGISTER-RESIDENT rewrite.
// 1 block = 1 batch row. Thread t owns dim t for all 32 slots:
// mem is read from HBM exactly once (vr_[32], vi_[32] in VGPRs).
// All per-slot reductions = 5-step shfl butterfly (32-lane halves)
// + 8-entry LDS combine (padded [8][33] -> conflict-free).
// =====================================================================
DEVINL void ln_half(float (&v)[32], float zz,
                    const float* __restrict__ gam, const float* __restrict__ bet,
                    float* __restrict__ obase, int t, int wp, int hs,
                    float (*redA)[33], float (*redB)[33],
                    float* __restrict__ smn, float* __restrict__ srs,
                    const float* __restrict__ seff) {
    float keepU = 0.f, keepQ = 0.f;
    #pragma unroll
    for (int s = 0; s < 32; s++) {
        float eff = seff[s];                 // LDS broadcast (free)
        float x = v[s] + eff * (zz - v[s]);  // (1-eff)*m + eff*z
        v[s] = x;
        float su = x, sq = x * x;
        #pragma unroll
        for (int m = 1; m <= 16; m <<= 1) {
            su += __shfl_xor(su, m, 64);
            sq += __shfl_xor(sq, m, 64);
        }
        if (hs == s) { keepU = su; keepQ = sq; }
    }
    redA[wp][hs] = keepU;
    redB[wp][hs] = keepQ;
    __syncthreads();
    if (t < 32) {
        float su = 0.f, sq = 0.f;
        #pragma unroll
        for (int j = 0; j < 8; j++) { su += redA[j][t]; sq += redB[j][t]; }
        float mn = su * (1.f / 256.f);
        float va = sq * (1.f / 256.f) - mn * mn;
        smn[t] = mn; srs[t] = rsqrtf(va + 1e-5f);
    }
    __syncthreads();
    float gv = gam[t], bv = bet[t];
    #pragma unroll
    for (int s = 0; s < 32; s++)
        obase[(size_t)s * 256 + t] = (v[s] - smn[s]) * srs[s] * gv + bv;
    __syncthreads();   // guard redA/redB/smn/srs reuse by next half
}

__global__ __launch_bounds__(256, 4) void k_mem(
    const float* __restrict__ mem_r, const float* __restrict__ mem_i,
    const float* __restrict__ gr, const float* __restrict__ gi,
    const float* __restrict__ gateW, const float* __restrict__ gateB,
    const float* __restrict__ addrW, const float* __restrict__ addrB,
    const float* __restrict__ mgr, const float* __restrict__ mbr,
    const float* __restrict__ mgi, const float* __restrict__ mbi,
    float* __restrict__ out, float* __restrict__ sent) {
    __shared__ float redA[8][33];
    __shared__ float redB[8][33];
    __shared__ float redG[8];
    __shared__ float satt[32], seff[32], smn[32], srs[32];
    const int b = blockIdx.x, t = threadIdx.x;
    const int w = t >> 6, lane = t & 63;
    const int wp = (w << 1) | (lane >> 5);   // half-wave group id 0..7
    const int hs = lane & 31;                // slot this lane keeps
    const float* mr = mem_r + (size_t)b * 8192;
    const float* mi = mem_i + (size_t)b * 8192;
    const float zr = gr[(size_t)b * 256 + t];
    const float zi = gi[(size_t)b * 256 + t];

    // ---- single coalesced read of mem into registers ----
    float vr_[32], vi_[32];
    #pragma unroll
    for (int s = 0; s < 32; s++) vr_[s] = mr[s * 256 + t];
    #pragma unroll
    for (int s = 0; s < 32; s++) vi_[s] = mi[s * 256 + t];

    // ---- sim per-slot reduction (registers only) ----
    {
        float keepS = 0.f;
        #pragma unroll
        for (int s = 0; s < 32; s++) {
            float ps = vr_[s] * zr + vi_[s] * zi;
            #pragma unroll
            for (int m = 1; m <= 16; m <<= 1) ps += __shfl_xor(ps, m, 64);
            if (hs == s) keepS = ps;
        }
        redA[wp][hs] = keepS;
    }
    // ---- ww logit per-slot reduction (addrW from L2, partial unroll) ----
    {
        float keepW = 0.f;
        #pragma unroll 4
        for (int s = 0; s < 32; s++) {
            float pw = addrW[s * 512 + t] * zr + addrW[s * 512 + 256 + t] * zi;
            #pragma unroll
            for (int m = 1; m <= 16; m <<= 1) pw += __shfl_xor(pw, m, 64);
            if (hs == s) keepW = pw;
        }
        redB[wp][hs] = keepW;
    }
    // ---- write-gate reduction ----
    {
        float pg = gateW[t] * zr + gateW[256 + t] * zi;
        #pragma unroll
        for (int m = 1; m <= 16; m <<= 1) pg += __shfl_xor(pg, m, 64);
        if (hs == 0) redG[wp] = pg;
    }
    __syncthreads();

    // ---- wave-parallel softmaxes + entropy + gate (lanes 0..31) ----
    if (t < 32) {
        float sim = 0.f, wwl = addrB[t], g = gateB[0];
        #pragma unroll
        for (int j = 0; j < 8; j++) { sim += redA[j][t]; wwl += redB[j][t]; g += redG[j]; }
        float wg = sigmoidf_(g);
        // sim softmax (32 lanes)
        float mx = sim;
        #pragma unroll
        for (int m = 1; m <= 16; m <<= 1) mx = fmaxf(mx, __shfl_xor(mx, m, 64));
        float e = __expf(sim - mx), su = e;
        #pragma unroll
        for (int m = 1; m <= 16; m <<= 1) su += __shfl_xor(su, m, 64);
        satt[t] = e / su;
        // ww softmax + entropy
        mx = wwl;
        #pragma unroll
        for (int m = 1; m <= 16; m <<= 1) mx = fmaxf(mx, __shfl_xor(mx, m, 64));
        e = __expf(wwl - mx); su = e;
        #pragma unroll
        for (int m = 1; m <= 16; m <<= 1) su += __shfl_xor(su, m, 64);
        float wv = e / su;
        seff[t] = wg * wv;
        float ent = -wv * __logf(wv + 1e-10f);
        #pragma unroll
        for (int m = 1; m <= 16; m <<= 1) ent += __shfl_xor(ent, m, 64);
        if (t == 0) atomicAdd(sent, ent * (1.f / 4096.f));
    }
    __syncthreads();

    // ---- content read (registers + LDS broadcast) ----
    {
        float rr = 0.f, ri = 0.f;
        #pragma unroll
        for (int s = 0; s < 32; s++) { float a = satt[s]; rr += a * vr_[s]; ri += a * vi_[s]; }
        float* om = out + (size_t)b * 2560 + 1024;
        om[t] = rr; om[256 + t] = ri;
    }

    // ---- gated write + LayerNorm, real then imag ----
    ln_half(vr_, zr, mgr, mbr, out + OUT_NMR + (size_t)b * 8192,
            t, wp, hs, redA, redB, smn, srs, seff);
    ln_half(vi_, zi, mgi, mbi, out + OUT_NMI + (size_t)b * 8192,
            t, wp, hs, redA, redB, smn, srs, seff);
}

// =====================================================================
// scalars
// =====================================================================
__global__ __launch_bounds__(256) void k_scalars(const int* __restrict__ hist,
                                                 const float* __restrict__ sent,
                                                 float* __restrict__ out) {
    int t = threadIdx.x;
    float local = 0.f;
    for (int k = t; k < 8192; k += 256) {
        float p = (float)hist[k] * (1.f / 4096.f);
        local += -p * __logf(p + 1e-10f);
    }
    __shared__ float red[4];
    for (int m = 1; m < 64; m <<= 1) local += __shfl_xor(local, m, 64);
    if ((t & 63) == 0) red[t >> 6] = local;
    __syncthreads();
    if (t == 0) {
        float bent = (red[0] + red[1] + red[2] + red[3]) / logf(8192.f);
        out[OUT_BENT] = bent;
        out[OUT_SENT] = sent[0];
    }
}

// =====================================================================
extern "C" void kernel_launch(void* const* d_in, const int* in_sizes, int n_in,
                              void* d_out, int out_size, void* d_ws, size_t ws_size,
                              hipStream_t stream) {
    const float* x_t_r = (const float*)d_in[0];
    const float* x_t_i = (const float*)d_in[1];
    const float* gw_r  = (const float*)d_in[2];
    const float* gw_i  = (const float*)d_in[3];
    const float* mem_r = (const float*)d_in[4];
    const float* mem_i = (const float*)d_in[5];
    const float* ig    = (const float*)d_in[6];
    const float* emb   = (const float*)d_in[7];
    const float* visp  = (const float*)d_in[8];
    const float* audp  = (const float*)d_in[9];
    const float* gateW = (const float*)d_in[10];
    const float* gateB = (const float*)d_in[11];
    const float* addrW = (const float*)d_in[12];
    const float* addrB = (const float*)d_in[13];
    const float* mgr   = (const float*)d_in[14];
    const float* mbr   = (const float*)d_in[15];
    const float* mgi   = (const float*)d_in[16];
    const float* mbi   = (const float*)d_in[17];

    char* w = (char*)d_ws;
    float*  gr    = (float*)(w + WS_GR);
    float*  gi    = (float*)(w + WS_GI);
    ushort* z2h   = (ushort*)(w + WS_Z2H);
    ushort* z2l   = (ushort*)(w + WS_Z2L);
    ushort* eh    = (ushort*)(w + WS_EH);
    ushort* el    = (ushort*)(w + WS_EL);
    float*  e2    = (float*)(w + WS_E2);
    ushort* Wbig  = (ushort*)(w + WS_WBIG);
    float*  biasv = (float*)(w + WS_BIAS);
    ushort* palc  = (ushort*)(w + WS_PALC);
    ushort* visT  = (ushort*)(w + WS_VIST);
    ushort* audT  = (ushort*)(w + WS_AUDT);
    float*  pval  = (float*)(w + WS_PVAL);
    int*    pidx  = (int*)(w + WS_PIDX);
    int*    hist  = (int*)(w + WS_HIST);
    float*  sent  = (float*)(w + WS_SENT);
    ushort* CLb   = (ushort*)(w + WS_CL);
    float*  logit = (float*)(w + WS_LOGIT);
    ushort* attn  = (ushort*)(w + WS_ATTN);
    float*  vis   = (float*)(w + WS_VIS);
    float*  aud   = (float*)(w + WS_AUD);
    float*  out   = (float*)d_out;

    hipMemsetAsync(w + WS_HIST, 0, 8192 * sizeof(int), stream);
    hipMemsetAsync(w + WS_SENT, 0, sizeof(float), stream);

    // prep
    k_prep_vq<<<KN / 4, 256, 0, stream>>>(emb, eh, el, e2);
    for (int p = 0; p < 5; p++) {
        k_prep_wbig<<<1024, 256, 0, stream>>>(
            (const float*)d_in[18 + p * 4], (const float*)d_in[19 + p * 4],
            (const float*)d_in[20 + p * 4], (const float*)d_in[21 + p * 4],
            Wbig + (size_t)p * 512 * 512, biasv + p * 512);
    }
    k_prep_palcat<<<1024, 256, 0, stream>>>(visp, audp, palc);
    k_prep_palT<<<512, 256, 0, stream>>>(visp, audp, visT, audT);

    // gate blend
    k_gate<<<BN, 256, 0, stream>>>(x_t_r, x_t_i, gw_r, gw_i, ig, gr, gi, z2h, z2l);

    // VQ
    k_vq_gemm<<<dim3(64, 32), 256, 0, stream>>>(z2h, z2l, eh, el, e2, pval, pidx);
    k_vqfin<<<BN, 256, 0, stream>>>(pval, pidx, emb, gr, gi, out, hist);

    // complex linears (all 5 fused, bf16 out), then hermitian/critic epilogue
    k_gemm<<<dim3(20, 32), 256, 0, stream>>>(z2h, 512, Wbig, 512, CLb, 2560, 512, biasv, 1);
    k_hermit<<<BN, 256, 0, stream>>>(CLb, out);

    // palette attention: logits from CL cols [1536,2048) (= sr|si)
    k_gemm<<<dim3(4, 32), 256, 0, stream>>>(CLb + 1536, 2560, palc, 512, logit, 512, 512, nullptr, 0);
    k_smax<<<BN, 256, 0, stream>>>(logit, attn);
    k_gemm<<<dim3(4, 32), 256, 0, stream>>>(attn, 512, visT, 256, vis, 512, 256, nullptr, 0);
    k_gemm<<<dim3(4, 32), 256, 0, stream>>>(attn + 256, 512, audT, 256, aud, 512, 256, nullptr, 0);
    k_sout<<<BN, 256, 0, stream>>>(vis, aud, out);

    // associative memory
    k_mem<<<BN, 256, 0, stream>>>(mem_r, mem_i, gr, gi, gateW, gateB, addrW, addrB,
                                  mgr, mbr, mgi, mbi, out, sent);

    // scalars
    k_scalars<<<1, 256, 0, stream>>>(hist, sent, out);
}

// Round 2
// 1070.795 us; speedup vs baseline: 1.0133x; 1.0081x over previous
//
#include <hip/hip_runtime.h>
#include <hip/hip_bf16.h>
#include <math.h>

// ---------------- problem constants ----------------
#define BN 4096
#define DN 256
#define SN 32
#define KN 8192
#define AN 256
#define TWO_D 512

typedef unsigned short ushort;
using bf16x8 = __attribute__((ext_vector_type(8))) short;
using f32x4  = __attribute__((ext_vector_type(4))) float;

// ---------------- output layout (f32 elements, concatenated flat) ------------
#define OUT_MAIN 0ull                       // [B,5,512] = 10485760
#define OUT_NMR  10485760ull                // [B,32,256] = 33554432
#define OUT_NMI  44040192ull
#define OUT_IDX  77594624ull                // [B]
#define OUT_VQL  77598720ull                // [B]
#define OUT_BENT 77602816ull
#define OUT_SENT 77602817ull

// ---------------- ws layout (bytes), total 93MB ----------------
#define MBYTE (1024ull*1024ull)
#define WS_GR    (0ull)            // f32 [B*256]   4MB
#define WS_GI    (4ull*MBYTE)      // f32           4MB
#define WS_Z2H   (8ull*MBYTE)      // u16 [B*512]   4MB
#define WS_Z2L   (12ull*MBYTE)     // u16           4MB
#define WS_EH    (16ull*MBYTE)     // u16 [K*512]   8MB
#define WS_EL    (24ull*MBYTE)     // u16           8MB
#define WS_E2    (32ull*MBYTE)     // f32 [K]
#define WS_WBIG  (33ull*MBYTE)     // u16 [2560*512] 2.5MB
#define WS_BIAS  (36ull*MBYTE)     // f32 [2560]
#define WS_PALC  (37ull*MBYTE)     // u16 [512*512] 0.5MB
#define WS_VIST  (38ull*MBYTE)     // u16 [512*256]
#define WS_AUDT  (39ull*MBYTE)     // u16 [512*256]
#define WS_PVAL  (40ull*MBYTE)     // f32 [4096*128] 2MB
#define WS_PIDX  (42ull*MBYTE)     // i32 [4096*128] 2MB
#define WS_HIST  (44ull*MBYTE)     // i32 [8192]
#define WS_ENTV  (44ull*MBYTE + 128ull*1024ull) // f32 [4096] per-row slot entropy
#define WS_CL    (45ull*MBYTE)     // u16 [4096*2560] 20MB
#define WS_LOGIT (65ull*MBYTE)     // f32 [4096*512] 8MB
#define WS_ATTN  (73ull*MBYTE)     // u16 [4096*512] 4MB
#define WS_VIS   (77ull*MBYTE)     // f32 [4096*512] 8MB
#define WS_AUD   (85ull*MBYTE)     // f32 [4096*512] 8MB -> 93MB total

#define DEVINL __device__ __forceinline__

DEVINL ushort f2bf(float f) {
    union { float f; unsigned u; } v; v.f = f;
    unsigned r = v.u + 0x7fffu + ((v.u >> 16) & 1u);
    return (ushort)(r >> 16);
}
DEVINL float bf2f(ushort h) {
    union { unsigned u; float f; } v; v.u = ((unsigned)h) << 16;
    return v.f;
}
DEVINL float sigmoidf_(float x) { return 1.f / (1.f + __expf(-x)); }

// =====================================================================
// prep: split vq_emb into bf16 hi/lo + row norms  (1 wave per code row)
// =====================================================================
__global__ __launch_bounds__(256) void k_prep_vq(const float* __restrict__ emb,
                                                 ushort* __restrict__ eh,
                                                 ushort* __restrict__ el,
                                                 float* __restrict__ e2) {
    int t = threadIdx.x, w = t >> 6, lane = t & 63;
    int row = blockIdx.x * 4 + w;
    const float* er = emb + (size_t)row * 512;
    float acc = 0.f;
    #pragma unroll
    for (int j = 0; j < 8; j++) {
        int k = lane + 64 * j;
        float e = er[k];
        ushort h = f2bf(e);
        eh[(size_t)row * 512 + k] = h;
        el[(size_t)row * 512 + k] = f2bf(e - bf2f(h));
        acc += e * e;
    }
    for (int m = 1; m < 64; m <<= 1) acc += __shfl_xor(acc, m, 64);
    if (lane == 0) e2[row] = acc;
}

// =====================================================================
// prep: one complex-linear block of Wbig (512 rows x 512 cols) + bias
// =====================================================================
__global__ void k_prep_wbig(const float* __restrict__ Wr, const float* __restrict__ Wi,
                            const float* __restrict__ br, const float* __restrict__ bi,
                            ushort* __restrict__ Wb, float* __restrict__ bias) {
    int idx = blockIdx.x * 256 + threadIdx.x;   // < 512*512
    int j = idx >> 9, k = idx & 511;
    int part = j >> 8, jj = j & 255;
    float v;
    if (part == 0) v = (k < 256) ? Wr[jj * 256 + k] : -Wi[jj * 256 + (k - 256)];
    else           v = (k < 256) ? Wi[jj * 256 + k] :  Wr[jj * 256 + (k - 256)];
    Wb[idx] = f2bf(v);
    if (k == 0) bias[j] = part ? (br[jj] + bi[jj]) : (br[jj] - bi[jj]);
}

__global__ void k_prep_palcat(const float* __restrict__ vis, const float* __restrict__ aud,
                              ushort* __restrict__ palc) {
    int idx = blockIdx.x * 256 + threadIdx.x;   // < 512*512
    int a = idx >> 9, k = idx & 511;
    float v = (a < 256) ? vis[a * 512 + k] : aud[(a - 256) * 512 + k];
    palc[idx] = f2bf(v);
}
__global__ void k_prep_palT(const float* __restrict__ vis, const float* __restrict__ aud,
                            ushort* __restrict__ visT, ushort* __restrict__ audT) {
    int idx = blockIdx.x * 256 + threadIdx.x;   // < 512*256
    int j = idx >> 8, a = idx & 255;
    visT[j * 256 + a] = f2bf(vis[a * 512 + j]);
    audT[j * 256 + a] = f2bf(aud[a * 512 + j]);
}

// =====================================================================
// input gate blend
// =====================================================================
__global__ void k_gate(const float* __restrict__ xr, const float* __restrict__ xi,
                       const float* __restrict__ gwr, const float* __restrict__ gwi,
                       const float* __restrict__ ig,
                       float* __restrict__ gr, float* __restrict__ gi,
                       ushort* __restrict__ z2h, ushort* __restrict__ z2l) {
    int i = blockIdx.x * 256 + threadIdx.x;     // < B*256
    float a = sigmoidf_(ig[0]);
    float r  = a * gwr[i] + (1.f - a) * xr[i];
    float im = a * gwi[i] + (1.f - a) * xi[i];
    gr[i] = r; gi[i] = im;
    int b = i >> 8, d = i & 255;
    size_t z = (size_t)b * 512;
    ushort rh = f2bf(r);  z2h[z + d] = rh;       z2l[z + d] = f2bf(r - bf2f(rh));
    ushort ih = f2bf(im); z2h[z + 256 + d] = ih; z2l[z + 256 + d] = f2bf(im - bf2f(ih));
}

// =====================================================================
// VQ GEMM (bf16x3) + per-row per-64col-slot argmin of (|e|^2 - 2 z.e)
// =====================================================================
__global__ __launch_bounds__(256) void k_vq_gemm(
    const ushort* __restrict__ Zh, const ushort* __restrict__ Zl,
    const ushort* __restrict__ Eh, const ushort* __restrict__ El,
    const float* __restrict__ e2, float* __restrict__ pval, int* __restrict__ pidx) {
    __shared__ ushort Ah[128 * 40], Al[128 * 40], Bh[128 * 40], Bl[128 * 40];
    const int m0 = blockIdx.y * 128, n0 = blockIdx.x * 128;
    const int t = threadIdx.x;
    const int w = t >> 6, lane = t & 63, q = lane >> 4, ln = lane & 15;
    const int wm = w >> 1, wn = w & 1;
    f32x4 acc[4][4] = {};
    const int lrow = t >> 2, lcol = (t & 3) * 8;
    for (int k0 = 0; k0 < 512; k0 += 32) {
        __syncthreads();
        #pragma unroll
        for (int rep = 0; rep < 2; rep++) {
            int r = lrow + rep * 64;
            *(uint4*)(&Ah[r * 40 + lcol]) = *(const uint4*)(Zh + (size_t)(m0 + r) * 512 + k0 + lcol);
            *(uint4*)(&Al[r * 40 + lcol]) = *(const uint4*)(Zl + (size_t)(m0 + r) * 512 + k0 + lcol);
            *(uint4*)(&Bh[r * 40 + lcol]) = *(const uint4*)(Eh + (size_t)(n0 + r) * 512 + k0 + lcol);
            *(uint4*)(&Bl[r * 40 + lcol]) = *(const uint4*)(El + (size_t)(n0 + r) * 512 + k0 + lcol);
        }
        __syncthreads();
        bf16x8 ah[4], al[4], bh[4], bl[4];
        #pragma unroll
        for (int i = 0; i < 4; i++) {
            int ar = wm * 64 + i * 16 + ln;
            ah[i] = *(const bf16x8*)(&Ah[ar * 40 + q * 8]);
            al[i] = *(const bf16x8*)(&Al[ar * 40 + q * 8]);
            int br = wn * 64 + i * 16 + ln;
            bh[i] = *(const bf16x8*)(&Bh[br * 40 + q * 8]);
            bl[i] = *(const bf16x8*)(&Bl[br * 40 + q * 8]);
        }
        #pragma unroll
        for (int i = 0; i < 4; i++)
            #pragma unroll
            for (int j = 0; j < 4; j++) {
                acc[i][j] = __builtin_amdgcn_mfma_f32_16x16x32_bf16(ah[i], bh[j], acc[i][j], 0, 0, 0);
                acc[i][j] = __builtin_amdgcn_mfma_f32_16x16x32_bf16(ah[i], bl[j], acc[i][j], 0, 0, 0);
                acc[i][j] = __builtin_amdgcn_mfma_f32_16x16x32_bf16(al[i], bh[j], acc[i][j], 0, 0, 0);
            }
    }
    float e2v[4]; int cidx[4];
    #pragma unroll
    for (int j = 0; j < 4; j++) { cidx[j] = n0 + wn * 64 + j * 16 + ln; e2v[j] = e2[cidx[j]]; }
    #pragma unroll
    for (int i = 0; i < 4; i++) {
        #pragma unroll
        for (int reg = 0; reg < 4; reg++) {
            float bv = 3.4e38f; int bc = 0x7fffffff;
            #pragma unroll
            for (int j = 0; j < 4; j++) {
                float s = e2v[j] - 2.f * acc[i][j][reg];
                if (s < bv || (s == bv && cidx[j] < bc)) { bv = s; bc = cidx[j]; }
            }
            for (int m = 1; m < 16; m <<= 1) {
                float ov = __shfl_xor(bv, m, 64);
                int   oc = __shfl_xor(bc, m, 64);
                if (ov < bv || (ov == bv && oc < bc)) { bv = ov; bc = oc; }
            }
            if (ln == 0) {
                int r = m0 + wm * 64 + i * 16 + q * 4 + reg;
                int slot = blockIdx.x * 2 + wn;
                pval[(size_t)r * 128 + slot] = bv;
                pidx[(size_t)r * 128 + slot] = bc;
            }
        }
    }
}

// =====================================================================
// finalize: top-8 by MFMA score, exact f64 rescore, write idx/v_out/vq_loss
// 1 block = 1 row. ALL d_out writes are f32.
// =====================================================================
__global__ __launch_bounds__(256) void k_vqfin(
    const float* __restrict__ pval, const int* __restrict__ pidx,
    const float* __restrict__ emb, const float* __restrict__ gr,
    const float* __restrict__ gi, float* __restrict__ out, int* __restrict__ hist) {
    __shared__ float sz[512];
    __shared__ float sv[128];
    __shared__ int   scd[128];
    __shared__ int   topc[8];
    __shared__ double tsc[8];
    __shared__ int   sbc;
    int b = blockIdx.x, t = threadIdx.x;
    sz[t]       = gr[(size_t)b * 256 + t];
    sz[256 + t] = gi[(size_t)b * 256 + t];
    if (t < 128) { sv[t] = pval[(size_t)b * 128 + t]; scd[t] = pidx[(size_t)b * 128 + t]; }
    __syncthreads();
    if (t == 0) {   // serial top-8 selection among 128 candidates
        for (int j = 0; j < 8; j++) {
            float bv = 3.4e38f; int bi = 0;
            for (int m = 0; m < 128; m++) {
                float v = sv[m];
                if (v < bv || (v == bv && scd[m] < scd[bi])) { bv = v; bi = m; }
            }
            topc[j] = scd[bi];
            sv[bi] = 3.4e38f;
        }
    }
    __syncthreads();
    int w = t >> 6, lane = t & 63;
    for (int rep = 0; rep < 2; rep++) {
        int j = w + rep * 4;
        int c = topc[j];
        const float* e = emb + (size_t)c * 512;
        double acc = 0.0;
        #pragma unroll
        for (int u = 0; u < 8; u++) {
            int k2 = lane + u * 64;
            double d = (double)sz[k2] - (double)e[k2];
            acc += d * d;
        }
        for (int m = 1; m < 64; m <<= 1) acc += __shfl_xor(acc, m, 64);
        if (lane == 0) tsc[j] = acc;
    }
    __syncthreads();
    if (t == 0) {
        double bv = tsc[0]; int bc = topc[0];
        for (int j = 1; j < 8; j++)
            if (tsc[j] < bv || (tsc[j] == bv && topc[j] < bc)) { bv = tsc[j]; bc = topc[j]; }
        sbc = bc;
        out[OUT_IDX + b] = (float)bc;
        out[OUT_VQL + b] = (float)(0.25 * bv / 512.0);
        atomicAdd(&hist[bc], 1);
    }
    __syncthreads();
    const float* e = emb + (size_t)sbc * 512;
    float* om = out + (size_t)b * 2560;
    om[t]       = e[t];
    om[256 + t] = e[256 + t];
}

// =====================================================================
// generic bf16 GEMM: C[MxN] = A[MxKd]*B[NxKd]^T (+bias); f32 or bf16 out
// =====================================================================
__global__ __launch_bounds__(256) void k_gemm(
    const ushort* __restrict__ A, int lda,
    const ushort* __restrict__ Bm, int ldb,
    void* __restrict__ C, int ldc,
    int Kd, const float* __restrict__ bias, int obf) {
    __shared__ ushort As[128 * 40], Bs[128 * 40];
    const int m0 = blockIdx.y * 128, n0 = blockIdx.x * 128;
    const int t = threadIdx.x;
    const int w = t >> 6, lane = t & 63, q = lane >> 4, ln = lane & 15;
    const int wm = w >> 1, wn = w & 1;
    f32x4 acc[4][4] = {};
    const int lrow = t >> 2, lcol = (t & 3) * 8;
    for (int k0 = 0; k0 < Kd; k0 += 32) {
        __syncthreads();
        #pragma unroll
        for (int rep = 0; rep < 2; rep++) {
            int r = lrow + rep * 64;
            *(uint4*)(&As[r * 40 + lcol]) = *(const uint4*)(A + (size_t)(m0 + r) * lda + k0 + lcol);
            *(uint4*)(&Bs[r * 40 + lcol]) = *(const uint4*)(Bm + (size_t)(n0 + r) * ldb + k0 + lcol);
        }
        __syncthreads();
        bf16x8 af[4], bfr[4];
        #pragma unroll
        for (int i = 0; i < 4; i++) {
            af[i]  = *(const bf16x8*)(&As[(wm * 64 + i * 16 + ln) * 40 + q * 8]);
            bfr[i] = *(const bf16x8*)(&Bs[(wn * 64 + i * 16 + ln) * 40 + q * 8]);
        }
        #pragma unroll
        for (int i = 0; i < 4; i++)
            #pragma unroll
            for (int j = 0; j < 4; j++)
                acc[i][j] = __builtin_amdgcn_mfma_f32_16x16x32_bf16(af[i], bfr[j], acc[i][j], 0, 0, 0);
    }
    #pragma unroll
    for (int i = 0; i < 4; i++) {
        int r = m0 + wm * 64 + i * 16 + q * 4;
        #pragma unroll
        for (int j = 0; j < 4; j++) {
            int c = n0 + wn * 64 + j * 16 + ln;
            float bb = bias ? bias[c] : 0.f;
            #pragma unroll
            for (int reg = 0; reg < 4; reg++) {
                float v = acc[i][j][reg] + bb;
                if (obf) ((ushort*)C)[(size_t)(r + reg) * ldc + c] = f2bf(v);
                else     ((float*)C)[(size_t)(r + reg) * ldc + c] = v;
            }
        }
    }
}

// =====================================================================
// hermitian gate epilogue + critic (CL is bf16) ; 1 block = 1 row
// =====================================================================
__global__ __launch_bounds__(256) void k_hermit(const ushort* __restrict__ CL,
                                                float* __restrict__ out) {
    int b = blockIdx.x, t = threadIdx.x;
    const ushort* row = CL + (size_t)b * 2560;
    float qr = bf2f(row[t]), qi = bf2f(row[256 + t]);
    float kr = bf2f(row[512 + t]), ki = bf2f(row[768 + t]);
    float part = qr * kr + qi * ki;
    __shared__ float red[4];
    for (int m = 1; m < 64; m <<= 1) part += __shfl_xor(part, m, 64);
    if ((t & 63) == 0) red[t >> 6] = part;
    __syncthreads();
    float gate = sigmoidf_(red[0] + red[1] + red[2] + red[3]);
    float vr = bf2f(row[1024 + t]), vi = bf2f(row[1280 + t]);
    float* om = out + (size_t)b * 2560;
    om[512 + t] = vr * gate; om[512 + 256 + t] = vi * gate;
    float crr = bf2f(row[2048 + t]), cii = bf2f(row[2304 + t]);
    om[4 * 512 + t] = -cii; om[4 * 512 + 256 + t] = crr;
}

// =====================================================================
// palette softmax over each 256-half (1 block = 1 row)
// =====================================================================
__global__ __launch_bounds__(256) void k_smax(const float* __restrict__ L,
                                              ushort* __restrict__ attn) {
    int b = blockIdx.x, t = threadIdx.x;
    __shared__ float sred[8];
    for (int h = 0; h < 2; h++) {
        float x = L[(size_t)b * 512 + h * 256 + t];
        float mx = x;
        for (int m = 1; m < 64; m <<= 1) mx = fmaxf(mx, __shfl_xor(mx, m, 64));
        if ((t & 63) == 0) sred[t >> 6] = mx;
        __syncthreads();
        mx = fmaxf(fmaxf(sred[0], sred[1]), fmaxf(sred[2], sred[3]));
        float e = __expf(x - mx);
        float su = e;
        for (int m = 1; m < 64; m <<= 1) su += __shfl_xor(su, m, 64);
        if ((t & 63) == 0) sred[4 + (t >> 6)] = su;
        __syncthreads();
        su = sred[4] + sred[5] + sred[6] + sred[7];
        attn[(size_t)b * 512 + h * 256 + t] = f2bf(e / su);
        __syncthreads();
    }
}

__global__ void k_sout(const float* __restrict__ vis, const float* __restrict__ aud,
                       float* __restrict__ out) {
    int i = blockIdx.x * 256 + threadIdx.x;  // < B*256
    int b = i >> 8, d = i & 255;
    const float* v = vis + (size_t)b * 512;
    const float* a = aud + (size_t)b * 512;
    float* om = out + (size_t)b * 2560 + 3 * 512;
    om[d]       = v[d] - a[256 + d];
    om[256 + d] = v[256 + d] + a[d];
}

// =====================================================================
// fused associative memory — register-resident; NO shared-address atomic.
// 1 block = 1 batch row. Thread t owns dim t for all 32 slots.
// Per-row slot entropy goes to entv[b]; k_scalars sums it.
// =====================================================================
DEVINL void ln_half(float (&v)[32], float zz,
                    const float* __restrict__ gam, const float* __restrict__ bet,
                    float* __restrict__ obase, int t, int wp, int hs,
                    float (*redA)[33], float (*redB)[33],
                    float* __restrict__ smn, float* __restrict__ srs,
                    const float* __restrict__ seff) {
    float keepU = 0.f, keepQ = 0.f;
    #pragma unroll
    for (int s = 0; s < 32; s++) {
        float eff = seff[s];                 // LDS broadcast (free)
        float x = v[s] + eff * (zz - v[s]);  // (1-eff)*m + eff*z
        v[s] = x;
        float su = x, sq = x * x;
        #pragma unroll
        for (int m = 1; m <= 16; m <<= 1) {
            su += __shfl_xor(su, m, 64);
            sq += __shfl_xor(sq, m, 64);
        }
        if (hs == s) { keepU = su; keepQ = sq; }
    }
    redA[wp][hs] = keepU;
    redB[wp][hs] = keepQ;
    __syncthreads();
    if (t < 32) {
        float su = 0.f, sq = 0.f;
        #pragma unroll
        for (int j = 0; j < 8; j++) { su += redA[j][t]; sq += redB[j][t]; }
        float mn = su * (1.f / 256.f);
        float va = sq * (1.f / 256.f) - mn * mn;
        smn[t] = mn; srs[t] = rsqrtf(va + 1e-5f);
    }
    __syncthreads();
    float gv = gam[t], bv = bet[t];
    #pragma unroll
    for (int s = 0; s < 32; s++)
        obase[(size_t)s * 256 + t] = (v[s] - smn[s]) * srs[s] * gv + bv;
    __syncthreads();   // guard redA/redB/smn/srs reuse by next half
}

__global__ __launch_bounds__(256, 4) void k_mem(
    const float* __restrict__ mem_r, const float* __restrict__ mem_i,
    const float* __restrict__ gr, const float* __restrict__ gi,
    const float* __restrict__ gateW, const float* __restrict__ gateB,
    const float* __restrict__ addrW, const float* __restrict__ addrB,
    const float* __restrict__ mgr, const float* __restrict__ mbr,
    const float* __restrict__ mgi, const float* __restrict__ mbi,
    float* __restrict__ out, float* __restrict__ entv) {
    __shared__ float redA[8][33];
    __shared__ float redB[8][33];
    __shared__ float redG[8];
    __shared__ float satt[32], seff[32], smn[32], srs[32];
    const int b = blockIdx.x, t = threadIdx.x;
    const int w = t >> 6, lane = t & 63;
    const int wp = (w << 1) | (lane >> 5);   // half-wave group id 0..7
    const int hs = lane & 31;                // slot this lane keeps
    const float* mr = mem_r + (size_t)b * 8192;
    const float* mi = mem_i + (size_t)b * 8192;
    const float zr = gr[(size_t)b * 256 + t];
    const float zi = gi[(size_t)b * 256 + t];

    // ---- single coalesced read of mem into registers ----
    float vr_[32], vi_[32];
    #pragma unroll
    for (int s = 0; s < 32; s++) vr_[s] = mr[s * 256 + t];
    #pragma unroll
    for (int s = 0; s < 32; s++) vi_[s] = mi[s * 256 + t];

    // ---- sim per-slot reduction (registers only) ----
    {
        float keepS = 0.f;
        #pragma unroll
        for (int s = 0; s < 32; s++) {
            float ps = vr_[s] * zr + vi_[s] * zi;
            #pragma unroll
            for (int m = 1; m <= 16; m <<= 1) ps += __shfl_xor(ps, m, 64);
            if (hs == s) keepS = ps;
        }
        redA[wp][hs] = keepS;
    }
    // ---- ww logit per-slot reduction (addrW from L2, partial unroll) ----
    {
        float keepW = 0.f;
        #pragma unroll 4
        for (int s = 0; s < 32; s++) {
            float pw = addrW[s * 512 + t] * zr + addrW[s * 512 + 256 + t] * zi;
            #pragma unroll
            for (int m = 1; m <= 16; m <<= 1) pw += __shfl_xor(pw, m, 64);
            if (hs == s) keepW = pw;
        }
        redB[wp][hs] = keepW;
    }
    // ---- write-gate reduction ----
    {
        float pg = gateW[t] * zr + gateW[256 + t] * zi;
        #pragma unroll
        for (int m = 1; m <= 16; m <<= 1) pg += __shfl_xor(pg, m, 64);
        if (hs == 0) redG[wp] = pg;
    }
    __syncthreads();

    // ---- wave-parallel softmaxes + entropy + gate (lanes 0..31) ----
    if (t < 32) {
        float sim = 0.f, wwl = addrB[t], g = gateB[0];
        #pragma unroll
        for (int j = 0; j < 8; j++) { sim += redA[j][t]; wwl += redB[j][t]; g += redG[j]; }
        float wg = sigmoidf_(g);
        // sim softmax (32 lanes)
        float mx = sim;
        #pragma unroll
        for (int m = 1; m <= 16; m <<= 1) mx = fmaxf(mx, __shfl_xor(mx, m, 64));
        float e = __expf(sim - mx), su = e;
        #pragma unroll
        for (int m = 1; m <= 16; m <<= 1) su += __shfl_xor(su, m, 64);
        satt[t] = e / su;
        // ww softmax + entropy
        mx = wwl;
        #pragma unroll
        for (int m = 1; m <= 16; m <<= 1) mx = fmaxf(mx, __shfl_xor(mx, m, 64));
        e = __expf(wwl - mx); su = e;
        #pragma unroll
        for (int m = 1; m <= 16; m <<= 1) su += __shfl_xor(su, m, 64);
        float wv = e / su;
        seff[t] = wg * wv;
        float ent = -wv * __logf(wv + 1e-10f);
        #pragma unroll
        for (int m = 1; m <= 16; m <<= 1) ent += __shfl_xor(ent, m, 64);
        if (t == 0) entv[b] = ent;   // contention-free per-row store
    }
    __syncthreads();

    // ---- content read (registers + LDS broadcast) ----
    {
        float rr = 0.f, ri = 0.f;
        #pragma unroll
        for (int s = 0; s < 32; s++) { float a = satt[s]; rr += a * vr_[s]; ri += a * vi_[s]; }
        float* om = out + (size_t)b * 2560 + 1024;
        om[t] = rr; om[256 + t] = ri;
    }

    // ---- gated write + LayerNorm, real then imag ----
    ln_half(vr_, zr, mgr, mbr, out + OUT_NMR + (size_t)b * 8192,
            t, wp, hs, redA, redB, smn, srs, seff);
    ln_half(vi_, zi, mgi, mbi, out + OUT_NMI + (size_t)b * 8192,
            t, wp, hs, redA, redB, smn, srs, seff);
}

// =====================================================================
// scalars: batch entropy from hist + mean slot entropy from entv
// =====================================================================
__global__ __launch_bounds__(256) void k_scalars(const int* __restrict__ hist,
                                                 const float* __restrict__ entv,
                                                 float* __restrict__ out) {
    int t = threadIdx.x;
    float local = 0.f;
    for (int k = t; k < 8192; k += 256) {
        float p = (float)hist[k] * (1.f / 4096.f);
        local += -p * __logf(p + 1e-10f);
    }
    float se = 0.f;
    for (int k = t; k < 4096; k += 256) se += entv[k];
    __shared__ float red[4], red2[4];
    for (int m = 1; m < 64; m <<= 1) {
        local += __shfl_xor(local, m, 64);
        se    += __shfl_xor(se, m, 64);
    }
    if ((t & 63) == 0) { red[t >> 6] = local; red2[t >> 6] = se; }
    __syncthreads();
    if (t == 0) {
        float bent = (red[0] + red[1] + red[2] + red[3]) / logf(8192.f);
        out[OUT_BENT] = bent;
        out[OUT_SENT] = (red2[0] + red2[1] + red2[2] + red2[3]) * (1.f / 4096.f);
    }
}

// =====================================================================
extern "C" void kernel_launch(void* const* d_in, const int* in_sizes, int n_in,
                              void* d_out, int out_size, void* d_ws, size_t ws_size,
                              hipStream_t stream) {
    const float* x_t_r = (const float*)d_in[0];
    const float* x_t_i = (const float*)d_in[1];
    const float* gw_r  = (const float*)d_in[2];
    const float* gw_i  = (const float*)d_in[3];
    const float* mem_r = (const float*)d_in[4];
    const float* mem_i = (const float*)d_in[5];
    const float* ig    = (const float*)d_in[6];
    const float* emb   = (const float*)d_in[7];
    const float* visp  = (const float*)d_in[8];
    const float* audp  = (const float*)d_in[9];
    const float* gateW = (const float*)d_in[10];
    const float* gateB = (const float*)d_in[11];
    const float* addrW = (const float*)d_in[12];
    const float* addrB = (const float*)d_in[13];
    const float* mgr   = (const float*)d_in[14];
    const float* mbr   = (const float*)d_in[15];
    const float* mgi   = (const float*)d_in[16];
    const float* mbi   = (const float*)d_in[17];

    char* w = (char*)d_ws;
    float*  gr    = (float*)(w + WS_GR);
    float*  gi    = (float*)(w + WS_GI);
    ushort* z2h   = (ushort*)(w + WS_Z2H);
    ushort* z2l   = (ushort*)(w + WS_Z2L);
    ushort* eh    = (ushort*)(w + WS_EH);
    ushort* el    = (ushort*)(w + WS_EL);
    float*  e2    = (float*)(w + WS_E2);
    ushort* Wbig  = (ushort*)(w + WS_WBIG);
    float*  biasv = (float*)(w + WS_BIAS);
    ushort* palc  = (ushort*)(w + WS_PALC);
    ushort* visT  = (ushort*)(w + WS_VIST);
    ushort* audT  = (ushort*)(w + WS_AUDT);
    float*  pval  = (float*)(w + WS_PVAL);
    int*    pidx  = (int*)(w + WS_PIDX);
    int*    hist  = (int*)(w + WS_HIST);
    float*  entv  = (float*)(w + WS_ENTV);
    ushort* CLb   = (ushort*)(w + WS_CL);
    float*  logit = (float*)(w + WS_LOGIT);
    ushort* attn  = (ushort*)(w + WS_ATTN);
    float*  vis   = (float*)(w + WS_VIS);
    float*  aud   = (float*)(w + WS_AUD);
    float*  out   = (float*)d_out;

    hipMemsetAsync(w + WS_HIST, 0, 8192 * sizeof(int), stream);

    // prep
    k_prep_vq<<<KN / 4, 256, 0, stream>>>(emb, eh, el, e2);
    for (int p = 0; p < 5; p++) {
        k_prep_wbig<<<1024, 256, 0, stream>>>(
            (const float*)d_in[18 + p * 4], (const float*)d_in[19 + p * 4],
            (const float*)d_in[20 + p * 4], (const float*)d_in[21 + p * 4],
            Wbig + (size_t)p * 512 * 512, biasv + p * 512);
    }
    k_prep_palcat<<<1024, 256, 0, stream>>>(visp, audp, palc);
    k_prep_palT<<<512, 256, 0, stream>>>(visp, audp, visT, audT);

    // gate blend
    k_gate<<<BN, 256, 0, stream>>>(x_t_r, x_t_i, gw_r, gw_i, ig, gr, gi, z2h, z2l);

    // VQ
    k_vq_gemm<<<dim3(64, 32), 256, 0, stream>>>(z2h, z2l, eh, el, e2, pval, pidx);
    k_vqfin<<<BN, 256, 0, stream>>>(pval, pidx, emb, gr, gi, out, hist);

    // complex linears (all 5 fused, bf16 out), then hermitian/critic epilogue
    k_gemm<<<dim3(20, 32), 256, 0, stream>>>(z2h, 512, Wbig, 512, CLb, 2560, 512, biasv, 1);
    k_hermit<<<BN, 256, 0, stream>>>(CLb, out);

    // palette attention: logits from CL cols [1536,2048) (= sr|si)
    k_gemm<<<dim3(4, 32), 256, 0, stream>>>(CLb + 1536, 2560, palc, 512, logit, 512, 512, nullptr, 0);
    k_smax<<<BN, 256, 0, stream>>>(logit, attn);
    k_gemm<<<dim3(4, 32), 256, 0, stream>>>(attn, 512, visT, 256, vis, 512, 256, nullptr, 0);
    k_gemm<<<dim3(4, 32), 256, 0, stream>>>(attn + 256, 512, audT, 256, aud, 512, 256, nullptr, 0);
    k_sout<<<BN, 256, 0, stream>>>(vis, aud, out);

    // associative memory
    k_mem<<<BN, 256, 0, stream>>>(mem_r, mem_i, gr, gi, gateW, gateB, addrW, addrB,
                                  mgr, mbr, mgi, mbi, out, entv);

    // scalars
    k_scalars<<<1, 256, 0, stream>>>(hist, entv, out);
}